// Round 2
// baseline (114.992 us; speedup 1.0000x reference)
//
#include <hip/hip_runtime.h>

typedef __attribute__((ext_vector_type(8))) _Float16 f16x8;
typedef __attribute__((ext_vector_type(4))) float f32x4;
typedef __attribute__((address_space(1))) const char gc_char;
typedef __attribute__((address_space(3))) char ls_char;

#define MFMA(a, b, c) __builtin_amdgcn_mfma_f32_16x16x32_f16((a), (b), (c), 0, 0, 0)
#define FENCE() asm volatile("" ::: "memory")
#define BARRIER() do { FENCE(); __builtin_amdgcn_s_barrier(); FENCE(); } while (0)
#define VMW(n) asm volatile("s_waitcnt vmcnt(" #n ")" ::: "memory")

static constexpr int SEQ = 4096;
static constexpr int EMB = 512;
static constexpr float QSCALE = 0.04419417382415922f; // 1/sqrt(512)

__device__ __forceinline__ void gl_lds16(const void* g, void* l) {
    __builtin_amdgcn_global_load_lds((gc_char*)g, (ls_char*)l, 16, 0, 0);
}

// ---------------- cast x (fp32 -> fp16), 8 elems/thread ----------------
__global__ void k_cast_x(const float* __restrict__ x, _Float16* __restrict__ xb) {
    long i = (long)blockIdx.x * 256 + threadIdx.x;
    const float4* p = (const float4*)x + i * 2;
    float4 a = p[0], b = p[1];
    f16x8 v;
    v[0] = (_Float16)a.x; v[1] = (_Float16)a.y; v[2] = (_Float16)a.z; v[3] = (_Float16)a.w;
    v[4] = (_Float16)b.x; v[5] = (_Float16)b.y; v[6] = (_Float16)b.z; v[7] = (_Float16)b.w;
    *(f16x8*)(xb + i * 8) = v;
}

// ---------------- transpose-cast W [512][N] -> WT [N][512] fp16 ----------------
__global__ void k_transpose_cast(const float* __restrict__ W, _Float16* __restrict__ WT, int Ncols) {
    int i = blockIdx.x * 256 + threadIdx.x;
    if (i >= Ncols * 512) return;
    int n = i >> 9, k = i & 511;
    WT[i] = (_Float16)W[k * Ncols + n];
}

// ================= QKV GEMM: 256x256 tile, BK=64, 8-phase counted-vmcnt =================
// A[16384,512]*BT[1536,512]^T + bias -> split Q(scaled)/K/V fp16.
// LDS: 2 dbuf x (A 32KB + B 32KB) = 128KB dynamic. 512 thr = 8 waves (2M x 4N).
// Half-tiles striped by read-quadrant: Ah = m-quadrant row stripes, Bh = n-quadrant col stripes.
// Stage order per K-tile kt (into other buffer, for kt+1): [Ah0@p0, Bh0@p1, Bh1@p2, Ah1@p3].
// Waits: vmcnt(4) at end of p0/p1/p3 -> 2 halves always in flight, never drain in loop.
__launch_bounds__(512, 2) __global__
void k_gemm_qkv(const _Float16* __restrict__ A, const _Float16* __restrict__ BT,
                const float* __restrict__ bias,
                _Float16* __restrict__ Qo, _Float16* __restrict__ Ko, _Float16* __restrict__ Vo) {
    extern __shared__ __align__(16) char smem[];
    const int tid = threadIdx.x, w = tid >> 6, lane = tid & 63, g = lane >> 4, f = lane & 15;
    const int wrow = w >> 2, wcol = w & 3;
    const int bid = blockIdx.x;
    const int swz = (bid & 7) * 48 + (bid >> 3); // XCD swizzle, 384 % 8 == 0 (bijective)
    const int brow = swz / 6, bcol = swz - brow * 6;
    const long row0 = (long)brow * 256;
    const int col0 = bcol * 256;
    const char* Abase = (const char*)A + row0 * 1024; // 512 fp16 = 1024B row stride
    const char* Bbase = (const char*)BT + (long)col0 * 1024;

    f32x4 acc[8][4] = {};
    f16x8 a[4][2], b[2][2];

    auto stageA = [&](int h, char* dstbuf, int kt) {
#pragma unroll
        for (int it = 0; it < 2; ++it) {
            int s = it * 512 + tid;
            int lr = s >> 3;
            int ch = (s & 7) ^ (lr & 7); // pre-swizzled global source
            int r = (lr & 63) | ((lr & 64) << 1) | (h << 6); // striped rows
            gl_lds16(Abase + (long)r * 1024 + kt * 128 + ch * 16, dstbuf + h * 16384 + s * 16);
        }
    };
    auto stageB = [&](int h, char* dstbuf, int kt) {
#pragma unroll
        for (int it = 0; it < 2; ++it) {
            int s = it * 512 + tid;
            int lr = s >> 3;
            int ch = (s & 7) ^ (lr & 7);
            int n = (lr & 31) | ((lr >> 5) << 6) | (h << 5); // striped cols
            gl_lds16(Bbase + (long)n * 1024 + kt * 128 + ch * 16, dstbuf + h * 16384 + s * 16);
        }
    };
    auto ldA = [&](const char* buf, int mq) {
#pragma unroll
        for (int mi = 0; mi < 4; ++mi)
#pragma unroll
            for (int ks = 0; ks < 2; ++ks) {
                int r = wrow * 128 + mq * 64 + mi * 16 + f;
                int half = (r >> 6) & 1, lr = (r & 63) | ((r & 128) >> 1);
                int cl = ks * 4 + g;
                a[mi][ks] = *(const f16x8*)(buf + half * 16384 + lr * 128 + ((cl ^ (lr & 7)) << 4));
            }
    };
    auto ldB = [&](const char* buf, int nq) {
#pragma unroll
        for (int ni = 0; ni < 2; ++ni)
#pragma unroll
            for (int ks = 0; ks < 2; ++ks) {
                int n = wcol * 64 + nq * 32 + ni * 16 + f;
                int half = (n >> 5) & 1, lr = (n & 31) | (((n >> 6) & 3) << 5);
                int cl = ks * 4 + g;
                b[ni][ks] = *(const f16x8*)(buf + half * 16384 + lr * 128 + ((cl ^ (lr & 7)) << 4));
            }
    };
    auto mfma16 = [&](int mq, int nq) {
        __builtin_amdgcn_s_setprio(1);
#pragma unroll
        for (int mi = 0; mi < 4; ++mi)
#pragma unroll
            for (int ni = 0; ni < 2; ++ni)
#pragma unroll
                for (int ks = 0; ks < 2; ++ks)
                    acc[mq * 4 + mi][nq * 2 + ni] = MFMA(a[mi][ks], b[ni][ks], acc[mq * 4 + mi][nq * 2 + ni]);
        __builtin_amdgcn_s_setprio(0);
    };

    // prologue: stage K-tile 0 fully into buf0; wait for Ah0+Bh0 (leave 2 halves in flight)
    {
        char* A0 = smem;
        char* B0 = smem + 32768;
        stageA(0, A0, 0); stageB(0, B0, 0); stageB(1, B0, 0); stageA(1, A0, 0);
    }
    VMW(4);
    BARRIER();

    for (int kt = 0; kt < 8; ++kt) {
        const char* Ac = smem + (kt & 1) * 65536;
        const char* Bc = Ac + 32768;
        char* An = smem + ((kt + 1) & 1) * 65536;
        char* Bn = An + 32768;
        const bool last = (kt == 7);
        // phase 0: quadrant (m0,n0); needs Ah0,Bh0 (waited at boundary)
        ldA(Ac, 0); ldB(Bc, 0);
        if (!last) stageA(0, An, kt + 1);
        BARRIER();
        mfma16(0, 0);
        if (!last) { VMW(4); } else { VMW(2); } // retire Bh1(kt)
        BARRIER();
        // phase 1: (m0,n1); needs Bh1
        ldB(Bc, 1);
        if (!last) stageB(0, Bn, kt + 1);
        BARRIER();
        mfma16(0, 1);
        if (!last) { VMW(4); } else { VMW(0); } // retire Ah1(kt)
        BARRIER();
        // phase 2: (m1,n0); needs Ah1
        ldA(Ac, 1); ldB(Bc, 0);
        if (!last) stageB(1, Bn, kt + 1);
        BARRIER();
        mfma16(1, 0);
        BARRIER();
        // phase 3: (m1,n1)
        ldB(Bc, 1);
        if (!last) stageA(1, An, kt + 1);
        BARRIER();
        mfma16(1, 1);
        if (!last) { VMW(4); } // boundary: retire Ah0+Bh0(kt+1)
        BARRIER();
    }

    // ---- epilogue: acc -> LDS (bias+scale, fp16, rotation swizzle) -> coalesced 16B stores ----
    float bv[4];
    const float sc = (col0 < 512) ? QSCALE : 1.0f;
#pragma unroll
    for (int ni = 0; ni < 4; ++ni) bv[ni] = bias[col0 + wcol * 64 + ni * 16 + f];
#pragma unroll
    for (int mi = 0; mi < 8; ++mi)
#pragma unroll
        for (int ni = 0; ni < 4; ++ni)
#pragma unroll
            for (int j = 0; j < 4; ++j) {
                int r = wrow * 128 + mi * 16 + g * 4 + j;
                int c = wcol * 64 + ni * 16 + f;
                float v = (acc[mi][ni][j] + bv[ni]) * sc;
                int pc = ((c >> 3) + ((r >> 2) & 7) * 2) & 31; // rotate 16B chunks by row
                *(_Float16*)(smem + r * 512 + pc * 16 + (c & 7) * 2) = (_Float16)v;
            }
    __syncthreads();
    _Float16* dst; int cofs;
    if (col0 < 512)       { dst = Qo; cofs = col0; }
    else if (col0 < 1024) { dst = Ko; cofs = col0 - 512; }
    else                  { dst = Vo; cofs = col0 - 1024; }
#pragma unroll
    for (int it = 0; it < 16; ++it) {
        int r = it * 16 + (tid >> 5);
        int ch = tid & 31;
        int pc = (ch + ((r >> 2) & 7) * 2) & 31;
        f16x8 v = *(const f16x8*)(smem + r * 512 + pc * 16);
        *(f16x8*)(dst + (row0 + r) * 512 + cofs + ch * 8) = v;
    }
}

// ================= out-projection GEMM (unchanged m97-style 128x128) =================
__launch_bounds__(256, 2) __global__
void k_gemm_out(const _Float16* __restrict__ A, const _Float16* __restrict__ BT,
                const float* __restrict__ bias, float* __restrict__ out) {
    __shared__ __align__(16) _Float16 As[128 * 64];
    __shared__ __align__(16) _Float16 Bs[128 * 64];
    const int tid = threadIdx.x, w = tid >> 6, lane = tid & 63, g = lane >> 4, f = lane & 15;
    const int wr = w >> 1, wc = w & 1;
    const long row0 = (long)blockIdx.x * 128, col0 = (long)blockIdx.y * 128;
    f32x4 acc[4][4] = {};
    const char* Ab = (const char*)(A + row0 * 512);
    const char* Bb = (const char*)(BT + col0 * 512);

    for (int kt = 0; kt < 8; ++kt) {
        __syncthreads();
        const char* Asrc = Ab + kt * 128;
        const char* Bsrc = Bb + kt * 128;
#pragma unroll
        for (int it = 0; it < 4; ++it) {
            int slot = it * 256 + tid;
            int r = slot >> 3, ch = slot & 7;
            int scol = (ch * 16) ^ ((r & 7) << 4);
            gl_lds16(Asrc + (long)r * 1024 + scol, (char*)As + (it * 256 + (tid & 0xC0)) * 16);
            gl_lds16(Bsrc + (long)r * 1024 + scol, (char*)Bs + (it * 256 + (tid & 0xC0)) * 16);
        }
        __syncthreads();
#pragma unroll
        for (int ks = 0; ks < 2; ++ks) {
            f16x8 af[4], bf[4];
#pragma unroll
            for (int mi = 0; mi < 4; ++mi) {
                int r = wr * 64 + mi * 16 + f;
                af[mi] = *(const f16x8*)((const char*)As + r * 128 + ((ks * 64 + g * 16) ^ ((r & 7) << 4)));
            }
#pragma unroll
            for (int ni = 0; ni < 4; ++ni) {
                int r = wc * 64 + ni * 16 + f;
                bf[ni] = *(const f16x8*)((const char*)Bs + r * 128 + ((ks * 64 + g * 16) ^ ((r & 7) << 4)));
            }
#pragma unroll
            for (int mi = 0; mi < 4; ++mi)
#pragma unroll
                for (int ni = 0; ni < 4; ++ni)
                    acc[mi][ni] = MFMA(af[mi], bf[ni], acc[mi][ni]);
        }
    }
#pragma unroll
    for (int mi = 0; mi < 4; ++mi)
#pragma unroll
        for (int ni = 0; ni < 4; ++ni) {
            long r0 = row0 + wr * 64 + mi * 16 + g * 4;
            int c = (int)col0 + wc * 64 + ni * 16 + f;
            float bv = bias[c];
#pragma unroll
            for (int j = 0; j < 4; ++j)
                out[(r0 + j) * 512 + c] = acc[mi][ni][j] + bv;
        }
}

// ---------------- windowed attention (unchanged) ----------------
__launch_bounds__(256, 2) __global__
void k_attn(const _Float16* __restrict__ Qb, const _Float16* __restrict__ Kb,
            const _Float16* __restrict__ Vb, _Float16* __restrict__ Ob) {
    __shared__ __align__(16) _Float16 Pl[64 * 200];
    __shared__ __align__(16) _Float16 VT[64 * 200];
    const int tid = threadIdx.x, w = tid >> 6, lane = tid & 63, g = lane >> 4, f = lane & 15;
    const int b = blockIdx.x >> 6, qt = blockIdx.x & 63;
    const int q0 = qt * 64, kbase = q0 - 64;

    const _Float16* qrow = Qb + ((long)(b * SEQ + q0 + w * 16 + f)) * EMB + g * 8;
    f16x8 qf[16];
#pragma unroll
    for (int ks = 0; ks < 16; ++ks) qf[ks] = *(const f16x8*)(qrow + ks * 32);

    const _Float16* kp[12];
#pragma unroll
    for (int t = 0; t < 12; ++t) {
        int key = kbase + t * 16 + f;
        key = min(max(key, 0), SEQ - 1);
        kp[t] = Kb + ((long)(b * SEQ + key)) * EMB + g * 8;
    }

    f32x4 sacc[12] = {};
#pragma unroll
    for (int ks = 0; ks < 16; ++ks) {
#pragma unroll
        for (int t = 0; t < 12; ++t)
            sacc[t] = MFMA(qf[ks], *(const f16x8*)(kp[t] + ks * 32), sacc[t]);
    }

    const int qr0 = q0 + w * 16 + g * 4;
    float m[4] = {-3e30f, -3e30f, -3e30f, -3e30f}, l[4] = {0.f, 0.f, 0.f, 0.f};
#pragma unroll
    for (int t = 0; t < 12; ++t) {
        int key = kbase + t * 16 + f;
        bool kv = (key >= 0) && (key < SEQ);
#pragma unroll
        for (int j = 0; j < 4; ++j) {
            int d = key - (qr0 + j);
            bool valid = kv && (d >= -64) && (d <= 64);
            float s = valid ? sacc[t][j] : -3e30f;
            sacc[t][j] = s;
            m[j] = fmaxf(m[j], s);
        }
    }
#pragma unroll
    for (int j = 0; j < 4; ++j) {
        m[j] = fmaxf(m[j], __shfl_xor(m[j], 1));
        m[j] = fmaxf(m[j], __shfl_xor(m[j], 2));
        m[j] = fmaxf(m[j], __shfl_xor(m[j], 4));
        m[j] = fmaxf(m[j], __shfl_xor(m[j], 8));
    }
#pragma unroll
    for (int t = 0; t < 12; ++t)
#pragma unroll
        for (int j = 0; j < 4; ++j) {
            float p = __expf(sacc[t][j] - m[j]);
            sacc[t][j] = p;
            l[j] += p;
        }
#pragma unroll
    for (int j = 0; j < 4; ++j) {
        l[j] += __shfl_xor(l[j], 1);
        l[j] += __shfl_xor(l[j], 2);
        l[j] += __shfl_xor(l[j], 4);
        l[j] += __shfl_xor(l[j], 8);
    }
    float rl[4];
#pragma unroll
    for (int j = 0; j < 4; ++j) rl[j] = 1.f / l[j];

#pragma unroll
    for (int t = 0; t < 12; ++t)
#pragma unroll
        for (int j = 0; j < 4; ++j)
            Pl[(w * 16 + g * 4 + j) * 200 + t * 16 + f] = (_Float16)sacc[t][j];
    __syncthreads();

    f16x8 pf[6];
#pragma unroll
    for (int kc = 0; kc < 6; ++kc)
        pf[kc] = *(const f16x8*)((const char*)Pl + (w * 16 + f) * 400 + kc * 64 + g * 16);

    int tkey = kbase + tid;
    tkey = min(max(tkey, 0), SEQ - 1);
    const _Float16* vrow = Vb + ((long)(b * SEQ + tkey)) * EMB;
    _Float16* obase = Ob + ((long)(b * SEQ + q0 + w * 16 + g * 4)) * EMB;

    for (int ec = 0; ec < 8; ++ec) {
        __syncthreads();
        if (tid < 192) {
#pragma unroll
            for (int p = 0; p < 8; ++p) {
                f16x8 vv = *(const f16x8*)(vrow + ec * 64 + p * 8);
#pragma unroll
                for (int i = 0; i < 8; ++i) VT[(p * 8 + i) * 200 + tid] = vv[i];
            }
        }
        __syncthreads();

        f32x4 pacc[4] = {};
#pragma unroll
        for (int kc = 0; kc < 6; ++kc)
#pragma unroll
            for (int ni = 0; ni < 4; ++ni) {
                f16x8 vf = *(const f16x8*)((const char*)VT + (ni * 16 + f) * 400 + kc * 64 + g * 16);
                pacc[ni] = MFMA(pf[kc], vf, pacc[ni]);
            }
#pragma unroll
        for (int ni = 0; ni < 4; ++ni)
#pragma unroll
            for (int j = 0; j < 4; ++j)
                obase[(long)j * EMB + ec * 64 + ni * 16 + f] = (_Float16)(pacc[ni][j] * rl[j]);
    }
}

extern "C" void kernel_launch(void* const* d_in, const int* in_sizes, int n_in,
                              void* d_out, int out_size, void* d_ws, size_t ws_size,
                              hipStream_t stream) {
    const float* x     = (const float*)d_in[0];
    const float* W_qkv = (const float*)d_in[1];
    const float* b_qkv = (const float*)d_in[2];
    const float* W_out = (const float*)d_in[3];
    const float* b_out = (const float*)d_in[4];

    char* ws = (char*)d_ws;
    _Float16* xb    = (_Float16*)(ws);                         // 16 MiB
    _Float16* WqkvT = (_Float16*)(ws + 16777216);              // 1.5 MiB
    _Float16* WoutT = (_Float16*)(ws + 16777216 + 1572864);    // 0.5 MiB
    _Float16* Qb    = (_Float16*)(ws + 18874368);              // 16 MiB
    _Float16* Kb    = (_Float16*)(ws + 18874368 + 16777216);   // 16 MiB
    _Float16* Vb    = (_Float16*)(ws + 18874368 + 33554432);   // 16 MiB
    _Float16* Ob    = xb; // reuse xb (dead after QKV GEMM)
    float* out = (float*)d_out;

    (void)hipFuncSetAttribute((const void*)k_gemm_qkv,
                              hipFuncAttributeMaxDynamicSharedMemorySize, 131072);

    k_cast_x<<<4096, 256, 0, stream>>>(x, xb);
    k_transpose_cast<<<3072, 256, 0, stream>>>(W_qkv, WqkvT, 1536);
    k_transpose_cast<<<1024, 256, 0, stream>>>(W_out, WoutT, 512);

    k_gemm_qkv<<<384, 512, 131072, stream>>>(xb, WqkvT, b_qkv, Qb, Kb, Vb);

    k_attn<<<256, 256, 0, stream>>>(Qb, Kb, Vb, Ob);

    dim3 g2(128, 4);
    k_gemm_out<<<g2, 256, 0, stream>>>(Ob, WoutT, b_out, out);
}